// Round 8
// baseline (258.634 us; speedup 1.0000x reference)
//
#include <hip/hip_runtime.h>

// ROI Align (max) — R8: R7 (persistent 8-item blocks) + explicit vmcnt(0)
// drain before the barrier.
//
// R7 failure analysis: global_load_lds is an async DMA tracked by vmcnt only.
// Inside the items loop the compiler did NOT emit s_waitcnt vmcnt(0) before
// s_barrier (it doesn't model the builtin's LDS write), so compute waves read
// LDS racing the DMA -> first launch passed, graph replays diverged.
// Fix: __builtin_amdgcn_s_waitcnt(0x0f70)  (vmcnt(0), expcnt/lgkmcnt no-wait)
// between staging issues and __syncthreads().
//
// Structure (unchanged from R7): block = (xcd octet, box n), loops over the
// octet's 8 channel-groups (32 channels). Tables loaded once per block;
// staging addresses are register adds. Keeps R4's XCD swizzle (FETCH 67 MB)
// and table-driven coords (VALUBusy 69->17%), R6's async staging (write
// conflicts 12.4M->5.2M).
//
// feature: (2, 256, 200, 304) fp32; boxes: (512,4); batch_idx: (512,) i32
// out: (512, 256, 7, 7) fp32. SPATIAL_SCALE=0.25, POOLED=7, SR=2, MODE=max.
//
// ws per-box layout (int32 units, stride 128 = 512 B; 256 KB total):
//  [0..27]   row byte-offsets (clamped row * Wc * 4), slot = 4*ph + 2*sy + which
//  [28]      xbase (multiple of 4)   [29] batch index
//  [32+4*s]  x-entry s=2*pw+sx: {c0, c1, bits(wx0), bits(wx1)} (c rel. xbase)
//  [96+2*s]  y-entry s=2*ph+sy: {bits(wy0), bits(wy1)}
// Validity folded into weights (w=0 outside (-1,H)/(-1,W)) == reference's
// where(valid, bil, 0). xbase = floor(first x sample) & ~3; span <= 48.3 ->
// c0 <= 52, c1 <= 53 < 64 staged cols.

#define POOLED 7

constexpr int Cc = 256;
constexpr int Hc = 200;
constexpr int Wc = 304;
constexpr int Nc = 512;
constexpr int PLANE   = Hc * Wc;          // 60800
constexpr int CELLS   = POOLED * POOLED;  // 49
constexpr int PER_BOX = Cc * CELLS;       // 12544
constexpr int CG      = 4;                // channels per item (1 per wave)
constexpr int ITEMS   = 8;                // cgs per block (one xcd octet)
constexpr int GRP_B   = 1040;             // 1 KB data + 16 B pad (260 dwords)
constexpr int CH_B    = 7 * GRP_B;        // 7280 B per channel
constexpr int WSTRIDE = 128;              // ints per box in ws

__device__ __forceinline__ void async_load16(const void* g, void* l) {
    __builtin_amdgcn_global_load_lds(
        (const __attribute__((address_space(1))) unsigned int*)g,
        (__attribute__((address_space(3))) unsigned int*)l, 16, 0, 0);
}

// s_waitcnt vmcnt(0) only: simm16 = expcnt(7)<<4 | lgkmcnt(15)<<8 | vmcnt(0)
__device__ __forceinline__ void wait_vmcnt0() {
    __builtin_amdgcn_s_waitcnt(0x0f70);
}

__global__ __launch_bounds__(256) void roi_setup_kernel(
    const float* __restrict__ boxes,
    const int*   __restrict__ batch_idx,
    int*         __restrict__ ws)
{
    int n = blockIdx.x * 4 + (threadIdx.x >> 6);   // 4 boxes per block
    int t = threadIdx.x & 63;

    float rsx = boxes[n * 4 + 0] * 0.25f;
    float rsy = boxes[n * 4 + 1] * 0.25f;
    float rex = boxes[n * 4 + 2] * 0.25f;
    float rey = boxes[n * 4 + 3] * 0.25f;
    float bin_w = fmaxf(rex - rsx, 1.0f) / (float)POOLED;
    float bin_h = fmaxf(rey - rsy, 1.0f) / (float)POOLED;

    float xf  = __fadd_rn(rsx, __fmul_rn(0.25f, bin_w));
    float xc0 = fminf(fmaxf(xf, 0.0f), (float)(Wc - 1));
    int xbase = ((int)floorf(xc0)) & ~3;

    int* W = ws + n * WSTRIDE;

    if (t < 14) {                                   // x-entries
        float px = (float)(t >> 1) + ((float)(t & 1) + 0.5f) * 0.5f;
        float fx = __fadd_rn(rsx, __fmul_rn(px, bin_w));
        bool vx  = (fx > -1.0f) && (fx < (float)Wc);
        float fxc = fminf(fmaxf(fx, 0.0f), (float)(Wc - 1));
        int   x0  = (int)floorf(fxc);
        float lx  = fxc - (float)x0;
        float hx  = 1.0f - lx;
        int4 e;
        e.x = x0 - xbase;
        e.y = min(x0 + 1, Wc - 1) - xbase;
        e.z = __float_as_int(vx ? hx : 0.0f);
        e.w = __float_as_int(vx ? lx : 0.0f);
        *(int4*)(W + 32 + 4 * t) = e;
    } else if (t >= 16 && t < 30) {                 // y-weight entries
        int s = t - 16;
        float py = (float)(s >> 1) + ((float)(s & 1) + 0.5f) * 0.5f;
        float fy = __fadd_rn(rsy, __fmul_rn(py, bin_h));
        bool vy  = (fy > -1.0f) && (fy < (float)Hc);
        float fyc = fminf(fmaxf(fy, 0.0f), (float)(Hc - 1));
        int   y0  = (int)floorf(fyc);
        float ly  = fyc - (float)y0;
        float hy  = 1.0f - ly;
        int2 e;
        e.x = __float_as_int(vy ? hy : 0.0f);
        e.y = __float_as_int(vy ? ly : 0.0f);
        *(int2*)(W + 96 + 2 * s) = e;
    } else if (t >= 32 && t < 60) {                 // row byte-offsets
        int slot = t - 32;
        int s    = slot >> 1;
        float py = (float)(s >> 1) + ((float)(s & 1) + 0.5f) * 0.5f;
        float fy = __fadd_rn(rsy, __fmul_rn(py, bin_h));
        float fyc = fminf(fmaxf(fy, 0.0f), (float)(Hc - 1));
        int   y0  = (int)floorf(fyc);
        int   row = (slot & 1) ? min(y0 + 1, Hc - 1) : y0;
        W[slot] = row * (Wc * 4);
    } else if (t == 60) {                           // meta
        W[28] = xbase;
        W[29] = batch_idx[n];
    }
}

__global__ __launch_bounds__(256) void roi_align_max_kernel(
    const float* __restrict__ feature,
    const int*   __restrict__ ws,
    float*       __restrict__ out)
{
    __shared__ char lds[CG * CH_B];                // 29,120 B -> 5 blocks/CU

    // Block = (xcd octet, box n); loops over the octet's 8 cgs.
    int p   = blockIdx.x;                          // 0..4095
    int xcd = p & 7;                               // consecutive p round-robin XCDs
    int n   = p >> 3;                              // 0..511

    const int* __restrict__ W = ws + n * WSTRIDE;
    int tid  = threadIdx.x;
    int cl   = tid >> 6;                           // channel within item
    int lane = tid & 63;
    int sb   = lane >> 4;                          // row within group 0..3
    int l16  = lane & 15;

    int xbase = W[28];
    int b     = W[29];

    // ---- Load ALL tables once per block (identical across the 8 items) ----
    int rowb[7];
    #pragma unroll
    for (int it = 0; it < 7; ++it)
        rowb[it] = W[it * 4 + sb];                 // 4-distinct broadcast load

    int cell = min(lane, 48);
    int ph   = cell / 7;
    int pw   = cell - ph * 7;
    const int4 ex0 = *(const int4*)(W + 32 + 8 * pw);      // sx=0
    const int4 ex1 = *(const int4*)(W + 32 + 8 * pw + 4);  // sx=1
    const int4 eyq = *(const int4*)(W + 96 + 4 * ph);      // {hy,ly} x {sy0,sy1}
    float wx00 = __int_as_float(ex0.z), wx01 = __int_as_float(ex0.w);
    float wx10 = __int_as_float(ex1.z), wx11 = __int_as_float(ex1.w);
    int c0a = ex0.x, c0b = ex1.x;

    int colb = min(xbase * 4 + l16 * 16, (Wc - 4) * 4);
    // First channel this wave touches: ch0 = xcd*32 + cl (item adds 4/iter).
    const char* gb = (const char*)feature
        + ((size_t)b * Cc + (size_t)(xcd * 32 + cl)) * (size_t)PLANE * 4
        + colb;
    char* lbase = lds + cl * CH_B;                 // wave-uniform
    float* op = out + (size_t)n * PER_BOX
              + (size_t)(xcd * 32 + cl) * CELLS + lane;

    #pragma unroll 1
    for (int item = 0; item < ITEMS; ++item) {
        // ---- Async staging: 7 instrs/wave, no dest VGPRs ----
        #pragma unroll
        for (int it = 0; it < 7; ++it)
            async_load16(gb + rowb[it], lbase + it * GRP_B);
        wait_vmcnt0();                             // drain DMA before barrier
        __syncthreads();

        // ---- Compute (identical to R6) ----
        if (lane < CELLS) {
            const float* L = (const float*)(lds + cl * CH_B + ph * GRP_B);
            float m = -INFINITY;
            {   // sy = 0: rows 0 (y0), 1 (y1)
                float wy0 = __int_as_float(eyq.x), wy1 = __int_as_float(eyq.y);
                const float* r0 = L;
                const float* r1 = L + 64;
                float a0 = r0[c0a], a1 = r0[c0a + 1];
                float b0 = r1[c0a], b1 = r1[c0a + 1];
                float t0 = fmaf(wx01, a1, wx00 * a0);
                float t1 = fmaf(wx01, b1, wx00 * b0);
                m = fmaxf(m, fmaf(wy1, t1, wy0 * t0));
                float c0_ = r0[c0b], c1_ = r0[c0b + 1];
                float d0 = r1[c0b], d1 = r1[c0b + 1];
                float u0 = fmaf(wx11, c1_, wx10 * c0_);
                float u1 = fmaf(wx11, d1, wx10 * d0);
                m = fmaxf(m, fmaf(wy1, u1, wy0 * u0));
            }
            {   // sy = 1: rows 2 (y0), 3 (y1)
                float wy0 = __int_as_float(eyq.z), wy1 = __int_as_float(eyq.w);
                const float* r0 = (const float*)(lds + cl * CH_B + ph * GRP_B) + 128;
                const float* r1 = r0 + 64;
                float a0 = r0[c0a], a1 = r0[c0a + 1];
                float b0 = r1[c0a], b1 = r1[c0a + 1];
                float t0 = fmaf(wx01, a1, wx00 * a0);
                float t1 = fmaf(wx01, b1, wx00 * b0);
                m = fmaxf(m, fmaf(wy1, t1, wy0 * t0));
                float c0_ = r0[c0b], c1_ = r0[c0b + 1];
                float d0 = r1[c0b], d1 = r1[c0b + 1];
                float u0 = fmaf(wx11, c1_, wx10 * c0_);
                float u1 = fmaf(wx11, d1, wx10 * d0);
                m = fmaxf(m, fmaf(wy1, u1, wy0 * u0));
            }
            *op = m;
        }
        __syncthreads();                           // LDS reuse guard

        gb += (size_t)CG * PLANE * 4;              // next 4 channels
        op += CG * CELLS;
    }
}

extern "C" void kernel_launch(void* const* d_in, const int* in_sizes, int n_in,
                              void* d_out, int out_size, void* d_ws, size_t ws_size,
                              hipStream_t stream) {
    const float* feature   = (const float*)d_in[0];
    const float* boxes     = (const float*)d_in[1];
    const int*   batch_idx = (const int*)d_in[2];
    float*       out       = (float*)d_out;
    int*         ws        = (int*)d_ws;           // 256 KB used

    roi_setup_kernel<<<Nc / 4, 256, 0, stream>>>(boxes, batch_idx, ws);

    int grid = 8 * Nc;                             // 4096 persistent-ish blocks
    roi_align_max_kernel<<<grid, 256, 0, stream>>>(feature, ws, out);
}